// Round 1
// baseline (223.325 us; speedup 1.0000x reference)
//
#include <hip/hip_runtime.h>
#include <cmath>

// irreps: 256x0e + 128x1e + 64x2e ; x row = 960 fp32
// Fused per-block kernel: linear -> normact(gelu) -> linear, bf16 MFMA.

typedef __bf16 v8bf  __attribute__((ext_vector_type(8)));
typedef float  v4f   __attribute__((ext_vector_type(4)));
typedef unsigned short u16x8 __attribute__((ext_vector_type(8)));

__device__ __forceinline__ unsigned short f2bf(float x) {
    union { float f; unsigned u; } v; v.f = x;
    unsigned r = v.u + 0x7FFFu + ((v.u >> 16) & 1u);   // RNE (inputs are finite)
    return (unsigned short)(r >> 16);
}

// --- pre-pass: W[u][w] fp32 -> WT[w][u] bf16, scaled by 1/sqrt(mul_in) -------
__global__ __launch_bounds__(256) void wt_prep(
    const float* __restrict__ w0, const float* __restrict__ w1,
    const float* __restrict__ w2, const float* __restrict__ w3,
    const float* __restrict__ w4, const float* __restrict__ w5,
    unsigned short* __restrict__ out)
{
    int t = blockIdx.x * 256 + threadIdx.x;
    if (t >= 172032) return;
    int s = (t < 65536) ? 0 : (t < 81920) ? 1 : (t < 86016) ? 2
          : (t < 151552) ? 3 : (t < 167936) ? 4 : 5;
    int base = (s == 0) ? 0 : (s == 1) ? 65536 : (s == 2) ? 81920
             : (s == 3) ? 86016 : (s == 4) ? 151552 : 167936;
    int lg   = (s == 0 || s == 3) ? 8 : (s == 1 || s == 4) ? 7 : 6;
    float scl = (s == 0 || s == 3) ? 0.0625f
              : (s == 1 || s == 4) ? 0.08838834764831845f : 0.125f;
    const float* p = (s == 0) ? w0 : (s == 1) ? w1 : (s == 2) ? w2
                   : (s == 3) ? w3 : (s == 4) ? w4 : w5;
    int loc = t - base;
    int w = loc >> lg;
    int u = loc & ((1 << lg) - 1);
    out[t] = f2bf(p[(u << lg) + w] * scl);   // WT[w][u] = W[u][w] * scale
}

// --- fused block kernel ------------------------------------------------------
// LDS layout: bf16 [i*64 + n][u], XOR-swizzled (idx ^= (row&7)<<3) to kill the
// stride-2U bank conflict on ds_read_b128 A-fragments (guide §6 G4).
template<int U, int D, int OFF>
__global__ __launch_bounds__(256) void fused_irrep(
    const float* __restrict__ x,
    const unsigned short* __restrict__ wt0,
    const unsigned short* __restrict__ wt1,
    float* __restrict__ out)
{
    constexpr int WIDTH = U * D;     // floats of this block per row
    constexpr int M   = 64 * D;      // LDS rows (i-major composite)
    constexpr int MT  = M / 16;      // m-tiles
    constexpr int NPW = U / 64;      // n-tiles per wave (4 waves split n)
    constexpr int KT  = U / 32;      // k-steps

    __shared__ unsigned short lds[M * U];

    const int tid  = threadIdx.x;
    const int lane = tid & 63;
    const int wid  = tid >> 6;
    const int row0 = blockIdx.x * 64;

    // ---- stage x -> LDS bf16 (de-interleave [n][u][i] -> [i*64+n][u]) ----
    if constexpr (D == 1) {
        #pragma unroll
        for (int o = 0; o < (64 * U / 8) / 256; ++o) {
            int oct = o * 256 + tid;
            int row = oct / (U / 8);
            int u0  = (oct % (U / 8)) * 8;
            const float4* p =
                reinterpret_cast<const float4*>(x + (long)(row0 + row) * 960 + OFF + u0);
            float4 fa = p[0], fb = p[1];
            u16x8 hv = { f2bf(fa.x), f2bf(fa.y), f2bf(fa.z), f2bf(fa.w),
                         f2bf(fb.x), f2bf(fb.y), f2bf(fb.z), f2bf(fb.w) };
            int idx = (row * U + u0) ^ ((row & 7) << 3);
            *reinterpret_cast<u16x8*>(&lds[idx]) = hv;   // ds_write_b128, swizzled
        }
    } else {
        #pragma unroll
        for (int e = 0; e < (64 * WIDTH) / (256 * 4); ++e) {
            int q   = (e * 256 + tid) * 4;
            int row = q / WIDTH;
            int c0  = q % WIDTH;
            float4 f = *reinterpret_cast<const float4*>(
                x + (long)(row0 + row) * 960 + OFF + c0);
            float fs[4] = {f.x, f.y, f.z, f.w};
            #pragma unroll
            for (int j = 0; j < 4; ++j) {
                int c = c0 + j;
                int u = c / D, i = c % D;          // constexpr divisor -> magic mul
                int R = i * 64 + row;
                int idx = (R * U + u) ^ ((R & 7) << 3);
                lds[idx] = f2bf(fs[j]);
            }
        }
    }
    __syncthreads();

    v4f acc[MT][NPW];

    // one GEMM layer: A[M,U] (LDS, swizzled) x WT[U_out][U] (global bf16, L2-hot)
    auto run_layer = [&](const unsigned short* __restrict__ wt, v4f (&A)[MT][NPW]) {
        #pragma unroll
        for (int mt = 0; mt < MT; ++mt)
            #pragma unroll
            for (int nt = 0; nt < NPW; ++nt) {
                v4f z = {0.f, 0.f, 0.f, 0.f};
                A[mt][nt] = z;
            }
        const int kcol = (lane >> 4) << 3;   // k-octet within K=32
        const int wcol = lane & 15;
        #pragma unroll
        for (int kt = 0; kt < KT; ++kt) {
            v8bf b[NPW];
            #pragma unroll
            for (int nt = 0; nt < NPW; ++nt) {
                int w = (wid * NPW + nt) * 16 + wcol;
                b[nt] = *reinterpret_cast<const v8bf*>(wt + w * U + kt * 32 + kcol);
            }
            #pragma unroll
            for (int mt = 0; mt < MT; ++mt) {
                int R = mt * 16 + wcol;
                int idx = (R * U + kt * 32 + kcol) ^ ((R & 7) << 3);
                v8bf a = *reinterpret_cast<const v8bf*>(&lds[idx]);
                #pragma unroll
                for (int nt = 0; nt < NPW; ++nt)
                    A[mt][nt] = __builtin_amdgcn_mfma_f32_16x16x32_bf16(
                        a, b[nt], A[mt][nt], 0, 0, 0);
            }
        }
    };

    run_layer(wt0, acc);
    __syncthreads();   // all waves done reading x tile before we overwrite it

    // ---- norm-act: per (row,w), n = ||.||_2 over i; factor = Phi(n) = gelu(n)/n
    // C/D layout: col = lane&15, row = (lane>>4)*4 + reg  -> all D components of
    // one (row,w) sit in the SAME lane/reg across the per-i accumulators.
    {
        const int g4   = (lane >> 4) << 2;
        const int wcol = lane & 15;
        #pragma unroll
        for (int nt = 0; nt < NPW; ++nt) {
            int w = (wid * NPW + nt) * 16 + wcol;
            #pragma unroll
            for (int nr = 0; nr < 4; ++nr) {
                #pragma unroll
                for (int r = 0; r < 4; ++r) {
                    float s = 0.f;
                    #pragma unroll
                    for (int i = 0; i < D; ++i) {
                        float v = acc[i * 4 + nr][nt][r];
                        s += v * v;
                    }
                    float fac = 0.5f * (1.0f + erff(sqrtf(s) * 0.70710678118654752f));
                    int rr = nr * 16 + g4 + r;
                    #pragma unroll
                    for (int i = 0; i < D; ++i) {
                        int R = i * 64 + rr;
                        int idx = (R * U + w) ^ ((R & 7) << 3);
                        lds[idx] = f2bf(acc[i * 4 + nr][nt][r] * fac);
                    }
                }
            }
        }
    }
    __syncthreads();

    run_layer(wt1, acc);

    // ---- store out fp32, re-interleaved [n][w*D + i] ----
    {
        const int g4   = (lane >> 4) << 2;
        const int wcol = lane & 15;
        #pragma unroll
        for (int nt = 0; nt < NPW; ++nt) {
            int w = (wid * NPW + nt) * 16 + wcol;
            #pragma unroll
            for (int i = 0; i < D; ++i) {
                #pragma unroll
                for (int nr = 0; nr < 4; ++nr) {
                    #pragma unroll
                    for (int r = 0; r < 4; ++r) {
                        int rr = nr * 16 + g4 + r;
                        out[(long)(row0 + rr) * 960 + OFF + w * D + i] =
                            acc[i * 4 + nr][nt][r];
                    }
                }
            }
        }
    }
}

extern "C" void kernel_launch(void* const* d_in, const int* in_sizes, int n_in,
                              void* d_out, int out_size, void* d_ws, size_t ws_size,
                              hipStream_t stream)
{
    const float* x  = (const float*)d_in[0];
    const float* W0 = (const float*)d_in[1];  // 256x256
    const float* W1 = (const float*)d_in[2];  // 128x128
    const float* W2 = (const float*)d_in[3];  // 64x64
    const float* W3 = (const float*)d_in[4];  // 256x256
    const float* W4 = (const float*)d_in[5];  // 128x128
    const float* W5 = (const float*)d_in[6];  // 64x64
    unsigned short* ws = (unsigned short*)d_ws;   // 344064 B of bf16 WT
    float* out = (float*)d_out;

    // bf16 transposed+scaled weights in workspace (element offsets):
    // L0: wt0 @ 0      (65536), wt1 @ 86016  (65536)
    // L1: wt0 @ 65536  (16384), wt1 @ 151552 (16384)
    // L2: wt0 @ 81920  ( 4096), wt1 @ 167936 ( 4096)
    wt_prep<<<672, 256, 0, stream>>>(W0, W1, W2, W3, W4, W5, ws);

    fused_irrep<256, 1,   0><<<1024, 256, 0, stream>>>(x, ws + 0,     ws + 86016,  out);
    fused_irrep<128, 3, 256><<<1024, 256, 0, stream>>>(x, ws + 65536, ws + 151552, out);
    fused_irrep< 64, 5, 640><<<1024, 256, 0, stream>>>(x, ws + 81920, ws + 167936, out);
}

// Round 2
// 161.749 us; speedup vs baseline: 1.3807x; 1.3807x over previous
//
#include <hip/hip_runtime.h>

// irreps: 256x0e + 128x1e + 64x2e ; x row = 960 fp32
// One merged kernel: per-WG runtime dispatch over the 3 irrep blocks,
// 32-row tiles, bf16 MFMA, linear -> normact(gelu exact via A&S erf) -> linear.

typedef __bf16 v8bf  __attribute__((ext_vector_type(8)));
typedef float  v4f   __attribute__((ext_vector_type(4)));
typedef unsigned short u16x8 __attribute__((ext_vector_type(8)));

__device__ __forceinline__ unsigned short f2bf(float x) {
    union { float f; unsigned u; } v; v.f = x;
    unsigned r = v.u + 0x7FFFu + ((v.u >> 16) & 1u);   // RNE (finite inputs)
    return (unsigned short)(r >> 16);
}
__device__ __forceinline__ unsigned pk2(float a, float b) {
    return (unsigned)f2bf(a) | ((unsigned)f2bf(b) << 16);
}

// Phi(n) = 0.5*(1+erf(n/sqrt(2))) = gelu(n)/n, n>=0.
// Abramowitz-Stegun 7.1.26, |err(erf)| <= 1.5e-7, branch-free.
__device__ __forceinline__ float phi_from_sq(float s) {
    float n = __builtin_amdgcn_sqrtf(s);
    float z = n * 0.70710678118654752f;
    float t = __builtin_amdgcn_rcpf(fmaf(0.3275911f, z, 1.0f));
    float p = t * fmaf(t, fmaf(t, fmaf(t, fmaf(t, 1.061405429f, -1.453152027f),
                                       1.421413741f), -0.284496736f), 0.254829592f);
    float e = __builtin_amdgcn_exp2f(z * z * -1.4426950408889634f);
    return fmaf(p * e, -0.5f, 1.0f);
}

// --- pre-pass: W[u][w] fp32 -> WT[w][u] bf16, scaled by 1/sqrt(mul_in) -------
__global__ __launch_bounds__(256) void wt_prep(
    const float* __restrict__ w0, const float* __restrict__ w1,
    const float* __restrict__ w2, const float* __restrict__ w3,
    const float* __restrict__ w4, const float* __restrict__ w5,
    unsigned short* __restrict__ out)
{
    int t = blockIdx.x * 256 + threadIdx.x;
    if (t >= 172032) return;
    int s = (t < 65536) ? 0 : (t < 81920) ? 1 : (t < 86016) ? 2
          : (t < 151552) ? 3 : (t < 167936) ? 4 : 5;
    int base = (s == 0) ? 0 : (s == 1) ? 65536 : (s == 2) ? 81920
             : (s == 3) ? 86016 : (s == 4) ? 151552 : 167936;
    int lg   = (s == 0 || s == 3) ? 8 : (s == 1 || s == 4) ? 7 : 6;
    float scl = (s == 0 || s == 3) ? 0.0625f
              : (s == 1 || s == 4) ? 0.08838834764831845f : 0.125f;
    const float* p = (s == 0) ? w0 : (s == 1) ? w1 : (s == 2) ? w2
                   : (s == 3) ? w3 : (s == 4) ? w4 : w5;
    int loc = t - base;
    int w = loc >> lg;
    int u = loc & ((1 << lg) - 1);
    out[t] = f2bf(p[(u << lg) + w] * scl);
}

// --- per-irrep worker (32-row tile) -----------------------------------------
// LDS: bf16 [i*32 + n][u], XOR-swizzled idx ^= (R&7)<<3 (elements) to kill the
// stride-2U bank conflict on ds_read_b128 A-fragments.
template<int U, int D, int OFF>
__device__ __forceinline__ void irrep_block(
    const float* __restrict__ x,
    const unsigned short* __restrict__ wt0,
    const unsigned short* __restrict__ wt1,
    float* __restrict__ out,
    unsigned short* __restrict__ lds,
    int tile)
{
    constexpr int M   = 32 * D;      // LDS rows
    constexpr int MT  = M / 16;      // m-tiles (= 2*D)
    constexpr int NPW = U / 64;      // n-tiles per wave (4 waves split n)
    constexpr int KT  = U / 32;      // k-steps

    const int tid  = threadIdx.x;
    const int lane = tid & 63;
    const int wid  = tid >> 6;
    const int row0 = tile * 32;

    // ---- stage x -> LDS bf16, de-interleaved [i*32+n][u] ----
    if constexpr (D == 1) {
        #pragma unroll
        for (int o = 0; o < (32 * (U / 8)) / 256; ++o) {
            int oct = o * 256 + tid;
            int row = oct / (U / 8);
            int u0  = (oct % (U / 8)) * 8;
            const float4* p =
                reinterpret_cast<const float4*>(x + (long)(row0 + row) * 960 + OFF + u0);
            float4 fa = p[0], fb = p[1];
            u16x8 hv = { f2bf(fa.x), f2bf(fa.y), f2bf(fa.z), f2bf(fa.w),
                         f2bf(fb.x), f2bf(fb.y), f2bf(fb.z), f2bf(fb.w) };
            int idx = (row * U + u0) ^ ((row & 7) << 3);
            *reinterpret_cast<u16x8*>(&lds[idx]) = hv;
        }
    } else {
        constexpr int PAIRS = U / 2;                  // u-pairs per row
        #pragma unroll
        for (int g = 0; g < (32 * PAIRS) / 256; ++g) {
            int gid = g * 256 + tid;
            int row = gid / PAIRS;
            int u0  = (gid % PAIRS) * 2;
            const float2* p = reinterpret_cast<const float2*>(
                x + (long)(row0 + row) * 960 + OFF + u0 * D);
            float f[2 * D];
            #pragma unroll
            for (int j = 0; j < D; ++j) { float2 q = p[j]; f[2*j] = q.x; f[2*j+1] = q.y; }
            #pragma unroll
            for (int i = 0; i < D; ++i) {
                int R = i * 32 + row;
                int idx = (R * U + u0) ^ ((R & 7) << 3);
                *reinterpret_cast<unsigned*>(&lds[idx]) = pk2(f[i], f[D + i]);
            }
        }
    }
    __syncthreads();

    v4f acc[MT][NPW];
    const int kcol = (lane >> 4) << 3;
    const int wcol = lane & 15;
    const int g4   = (lane >> 4) << 2;

    auto run_layer = [&](const unsigned short* __restrict__ wt) {
        #pragma unroll
        for (int mt = 0; mt < MT; ++mt)
            #pragma unroll
            for (int nt = 0; nt < NPW; ++nt) {
                v4f z = {0.f, 0.f, 0.f, 0.f};
                acc[mt][nt] = z;
            }
        #pragma unroll
        for (int kt = 0; kt < KT; ++kt) {
            v8bf b[NPW];
            #pragma unroll
            for (int nt = 0; nt < NPW; ++nt) {
                int w = (wid * NPW + nt) * 16 + wcol;
                b[nt] = *reinterpret_cast<const v8bf*>(wt + w * U + kt * 32 + kcol);
            }
            #pragma unroll
            for (int mt = 0; mt < MT; ++mt) {
                int R = mt * 16 + wcol;
                int idx = (R * U + kt * 32 + kcol) ^ ((R & 7) << 3);
                v8bf a = *reinterpret_cast<const v8bf*>(&lds[idx]);
                #pragma unroll
                for (int nt = 0; nt < NPW; ++nt)
                    acc[mt][nt] = __builtin_amdgcn_mfma_f32_16x16x32_bf16(
                        a, b[nt], acc[mt][nt], 0, 0, 0);
            }
        }
    };

    run_layer(wt0);
    __syncthreads();   // all waves done reading x before overwriting with H

    // ---- norm-act: n^2 over i sits in the SAME lane/reg across acc[(i<<1)|h] ----
    #pragma unroll
    for (int nt = 0; nt < NPW; ++nt) {
        int w = (wid * NPW + nt) * 16 + wcol;
        #pragma unroll
        for (int h = 0; h < 2; ++h) {
            #pragma unroll
            for (int r = 0; r < 4; ++r) {
                float s = 0.f;
                #pragma unroll
                for (int i = 0; i < D; ++i) {
                    float v = acc[(i << 1) | h][nt][r];
                    s += v * v;
                }
                float fac = phi_from_sq(s);
                int n = h * 16 + g4 + r;
                #pragma unroll
                for (int i = 0; i < D; ++i) {
                    int R = i * 32 + n;
                    int idx = (R * U + w) ^ ((R & 7) << 3);
                    lds[idx] = f2bf(acc[(i << 1) | h][nt][r] * fac);
                }
            }
        }
    }
    __syncthreads();

    run_layer(wt1);

    // ---- store fp32, per-lane contiguous D-float groups at out[n][OFF+w*D+i] ----
    #pragma unroll
    for (int nt = 0; nt < NPW; ++nt) {
        int w = (wid * NPW + nt) * 16 + wcol;
        #pragma unroll
        for (int h = 0; h < 2; ++h) {
            #pragma unroll
            for (int r = 0; r < 4; ++r) {
                int n = h * 16 + g4 + r;
                float* po = out + (long)(row0 + n) * 960 + OFF + w * D;
                #pragma unroll
                for (int i = 0; i < D; ++i)
                    po[i] = acc[(i << 1) | h][nt][r];
            }
        }
    }
}

// --- merged kernel: type = bid%3 interleaves irreps across the device --------
__global__ __launch_bounds__(256, 4) void fused_all(
    const float* __restrict__ x,
    const unsigned short* __restrict__ ws,
    float* __restrict__ out)
{
    __shared__ unsigned short lds[96 * 128];   // 24 KB, max over the 3 types
    int bid  = blockIdx.x;
    int type = bid % 3;
    int tile = bid / 3;
    if (type == 0)
        irrep_block<256, 1,   0>(x, ws + 0,     ws + 86016,  out, lds, tile);
    else if (type == 1)
        irrep_block<128, 3, 256>(x, ws + 65536, ws + 151552, out, lds, tile);
    else
        irrep_block< 64, 5, 640>(x, ws + 81920, ws + 167936, out, lds, tile);
}

extern "C" void kernel_launch(void* const* d_in, const int* in_sizes, int n_in,
                              void* d_out, int out_size, void* d_ws, size_t ws_size,
                              hipStream_t stream)
{
    const float* x  = (const float*)d_in[0];
    const float* W0 = (const float*)d_in[1];  // 256x256
    const float* W1 = (const float*)d_in[2];  // 128x128
    const float* W2 = (const float*)d_in[3];  // 64x64
    const float* W3 = (const float*)d_in[4];  // 256x256
    const float* W4 = (const float*)d_in[5];  // 128x128
    const float* W5 = (const float*)d_in[6];  // 64x64
    unsigned short* ws = (unsigned short*)d_ws;   // 344064 B of bf16 WT
    float* out = (float*)d_out;

    wt_prep<<<672, 256, 0, stream>>>(W0, W1, W2, W3, W4, W5, ws);
    fused_all<<<6144, 256, 0, stream>>>(x, ws, out);
}